// Round 1
// baseline (325.305 us; speedup 1.0000x reference)
//
#include <hip/hip_runtime.h>

namespace {

constexpr int L = 10000;   // links
constexpr int F = 8;       // input features
constexpr int H = 64;      // hidden size
constexpr int B = 32;      // batch

__device__ __forceinline__ float fsigmoid(float x) {
    return 1.0f / (1.0f + __expf(-x));
}
__device__ __forceinline__ float ftanh(float x) {
    // tanh(x) = 2*sigmoid(2x) - 1
    return 2.0f / (1.0f + __expf(-2.0f * x)) - 1.0f;
}

__global__ __launch_bounds__(256, 2)
void gcrnn_cell(const float* __restrict__ hidden, const float* __restrict__ xin,
                const float* __restrict__ Wrh, const float* __restrict__ Brh,
                const float* __restrict__ Wri, const float* __restrict__ Bri,
                const float* __restrict__ Wuh, const float* __restrict__ Buh,
                const float* __restrict__ Wui, const float* __restrict__ Bui,
                const float* __restrict__ Wnh, const float* __restrict__ Bnh,
                const float* __restrict__ Wni, const float* __restrict__ Bni,
                float* __restrict__ out)
{
    // XCD-chunked bijective swizzle: 10000 % 8 == 0, each XCD gets a
    // contiguous run of 1250 links -> adjacent j share L2 lines on one XCD.
    const int bid = blockIdx.x;
    const int j = (bid & 7) * (L / 8) + (bid >> 3);

    __shared__ __align__(16) float sXh[H][B];    // [i][b] = hidden[b,i,j]
    __shared__ __align__(16) float sXi[F][B];    // [i][b] = xin[b,i,j]
    __shared__ __align__(16) float sWrh[H][H];   // [i][k]
    __shared__ __align__(16) float sWuh[H][H];
    __shared__ __align__(16) float sWnh[H][H];
    __shared__ __align__(16) float sWri[F][H];
    __shared__ __align__(16) float sWui[F][H];
    __shared__ __align__(16) float sWni[F][H];

    const int t = threadIdx.x;

    // ---- stage hidden-weight tiles (contiguous, float4-coalesced, read-once)
    {
        const float4* sR = (const float4*)(Wrh + (size_t)j * H * H);
        const float4* sU = (const float4*)(Wuh + (size_t)j * H * H);
        const float4* sN = (const float4*)(Wnh + (size_t)j * H * H);
        float4* dR = (float4*)&sWrh[0][0];
        float4* dU = (float4*)&sWuh[0][0];
        float4* dN = (float4*)&sWnh[0][0];
#pragma unroll
        for (int n = 0; n < (H * H / 4) / 256; ++n) {
            const int idx = t + 256 * n;
            dR[idx] = sR[idx];
            dU[idx] = sU[idx];
            dN[idx] = sN[idx];
        }
        if (t < F * H / 4) {
            ((float4*)&sWri[0][0])[t] = ((const float4*)(Wri + (size_t)j * F * H))[t];
            ((float4*)&sWui[0][0])[t] = ((const float4*)(Wui + (size_t)j * F * H))[t];
            ((float4*)&sWni[0][0])[t] = ((const float4*)(Wni + (size_t)j * F * H))[t];
        }
    }

    // ---- stage activations (scattered 4B; adjacent-j blocks share lines)
#pragma unroll
    for (int n = 0; n < (H * B) / 256; ++n) {
        const int idx = t + 256 * n;
        const int i = idx >> 5;
        const int b = idx & 31;
        sXh[i][b] = hidden[(size_t)(b * H + i) * L + j];
    }
    {
        const int i = t >> 5;
        const int b = t & 31;
        sXi[i][b] = xin[(size_t)(b * F + i) * L + j];
    }
    __syncthreads();

    // thread -> output tile: k pair (2 cols) x b quad (4 rows)
    const int k0 = (t & 31) * 2;
    const int b0 = (t >> 5) * 4;

    float accR[4][2] = {};
    float accU[4][2] = {};
    float accN[4][2] = {};   // new_hidden gemm (pre reset-multiply)
    float accNI[4][2] = {};  // new_input gemm

    // fused 3-gate hidden GEMM over i: 1x b128 + 3x b64 LDS reads, 24 FMAs
#pragma unroll 8
    for (int i = 0; i < H; ++i) {
        const float4 x = *(const float4*)&sXh[i][b0];
        const float2 wr = *(const float2*)&sWrh[i][k0];
        const float2 wu = *(const float2*)&sWuh[i][k0];
        const float2 wn = *(const float2*)&sWnh[i][k0];
        const float xs[4] = {x.x, x.y, x.z, x.w};
#pragma unroll
        for (int b = 0; b < 4; ++b) {
            accR[b][0] += xs[b] * wr.x;  accR[b][1] += xs[b] * wr.y;
            accU[b][0] += xs[b] * wu.x;  accU[b][1] += xs[b] * wu.y;
            accN[b][0] += xs[b] * wn.x;  accN[b][1] += xs[b] * wn.y;
        }
    }
    // input GEMMs (i over 8); reset/update fold into accR/accU, new stays split
#pragma unroll
    for (int i = 0; i < F; ++i) {
        const float4 x = *(const float4*)&sXi[i][b0];
        const float2 wr = *(const float2*)&sWri[i][k0];
        const float2 wu = *(const float2*)&sWui[i][k0];
        const float2 wn = *(const float2*)&sWni[i][k0];
        const float xs[4] = {x.x, x.y, x.z, x.w};
#pragma unroll
        for (int b = 0; b < 4; ++b) {
            accR[b][0] += xs[b] * wr.x;  accR[b][1] += xs[b] * wr.y;
            accU[b][0] += xs[b] * wu.x;  accU[b][1] += xs[b] * wu.y;
            accNI[b][0] += xs[b] * wn.x; accNI[b][1] += xs[b] * wn.y;
        }
    }

    // biases for this thread's two k columns
    float bR[2], bU[2], bNH[2], bNI[2];
#pragma unroll
    for (int kk = 0; kk < 2; ++kk) {
        const size_t o = (size_t)(k0 + kk) * L + j;
        bR[kk]  = Brh[o] + Bri[o];
        bU[kk]  = Buh[o] + Bui[o];
        bNH[kk] = Bnh[o];
        bNI[kk] = Bni[o];
    }

#pragma unroll
    for (int b = 0; b < 4; ++b) {
#pragma unroll
        for (int kk = 0; kk < 2; ++kk) {
            const int k = k0 + kk;
            const float r = fsigmoid(accR[b][kk] + bR[kk]);
            const float u = fsigmoid(accU[b][kk] + bU[kk]);
            const float n = ftanh(r * (accN[b][kk] + bNH[kk]) + accNI[b][kk] + bNI[kk]);
            const float h = sXh[k][b0 + b];
            out[(size_t)((b0 + b) * H + k) * L + j] = (1.0f - u) * n + u * h;
        }
    }
}

} // namespace

extern "C" void kernel_launch(void* const* d_in, const int* in_sizes, int n_in,
                              void* d_out, int out_size, void* d_ws, size_t ws_size,
                              hipStream_t stream) {
    const float* hidden = (const float*)d_in[0];
    const float* xin    = (const float*)d_in[1];
    const float* Wrh    = (const float*)d_in[2];
    const float* Brh    = (const float*)d_in[3];
    const float* Wri    = (const float*)d_in[4];
    const float* Bri    = (const float*)d_in[5];
    const float* Wuh    = (const float*)d_in[6];
    const float* Buh    = (const float*)d_in[7];
    const float* Wui    = (const float*)d_in[8];
    const float* Bui    = (const float*)d_in[9];
    const float* Wnh    = (const float*)d_in[10];
    const float* Bnh    = (const float*)d_in[11];
    const float* Wni    = (const float*)d_in[12];
    const float* Bni    = (const float*)d_in[13];
    float* out = (float*)d_out;

    gcrnn_cell<<<L, 256, 0, stream>>>(hidden, xin,
                                      Wrh, Brh, Wri, Bri,
                                      Wuh, Buh, Wui, Bui,
                                      Wnh, Bnh, Wni, Bni,
                                      out);
}